// Round 10
// baseline (326.975 us; speedup 1.0000x reference)
//
#include <hip/hip_runtime.h>
#include <hip/hip_bf16.h>

#define N 8192
#define F 256
#define KSPLIT 8
#define JBLK (N / KSPLIT)    // 1024 cols per k3 block
#define NITER (JBLK / 64)    // 16 j-tiles of 64
#define LOG2E 1.4426950408889634f

using s16x8 = __attribute__((ext_vector_type(8))) short;
using f32x4 = __attribute__((ext_vector_type(4))) float;

static __device__ __forceinline__ unsigned short f2bf(float f) {
  unsigned int u = __float_as_uint(f);
  unsigned int r = u + 0x7fffu + ((u >> 16) & 1u);   // RNE
  return (unsigned short)(r >> 16);
}
static __device__ __forceinline__ float bf2f(unsigned short u) {
  return __uint_as_float(((unsigned int)u) << 16);
}
static __device__ __forceinline__ void glds16(const void* g, void* l) {
  __builtin_amdgcn_global_load_lds(
      (const __attribute__((address_space(1))) unsigned int*)g,
      (__attribute__((address_space(3))) unsigned int*)l, 16, 0, 0);
}

// ---------------- k0: Wt[f][k] = bf16(W[k][f]) ----------------
__global__ __launch_bounds__(256) void k0_wt(const float* __restrict__ W,
                                             unsigned short* __restrict__ Wt) {
  int k = blockIdx.x;
  int f = threadIdx.x;
  Wt[f * 256 + k] = f2bf(W[k * 256 + f]);
}

// ---------------- k1: Wh GEMM -> tiled/swizzled WhbT + fused s1,s2 (pre-scaled by log2e) ----
__global__ __launch_bounds__(256) void k1_wh(const float* __restrict__ h,
                                             const unsigned short* __restrict__ Wt,
                                             const float* __restrict__ a,
                                             char* __restrict__ WhbT,
                                             float* __restrict__ s1g,
                                             float* __restrict__ s2g) {
  __shared__ char lds[8192 + 32768];
  char* Alds = lds;
  char* Blds = lds + 8192;
  int t = threadIdx.x;
  int i0 = blockIdx.x * 64;
  int l = t & 63, w = t >> 6;
  int lr = l & 15, lk = l >> 4;
  f32x4 acc[4][4] = {};
  for (int kt = 0; kt < 4; ++kt) {
    int k0 = kt * 64;
    if (kt) __syncthreads();
#pragma unroll
    for (int c = 0; c < 4; ++c) {
      int flat = c * 256 + t;
      int i = flat >> 4, jc = flat & 15;
      float4 v = *reinterpret_cast<const float4*>(h + (size_t)(i0 + i) * 256 + k0 + jc * 4);
      ushort4 pk;
      pk.x = f2bf(v.x); pk.y = f2bf(v.y); pk.z = f2bf(v.z); pk.w = f2bf(v.w);
      *reinterpret_cast<ushort4*>(Alds + i * 128 + ((jc * 8) ^ ((i & 7) << 4))) = pk;
    }
#pragma unroll
    for (int c = 0; c < 8; ++c) {
      int idx = c * 256 + t;
      int fr = idx >> 3, kc = idx & 7;
      uint4 v = *reinterpret_cast<const uint4*>(Wt + fr * 256 + k0 + kc * 8);
      *reinterpret_cast<uint4*>(Blds + fr * 128 + ((kc * 16) ^ ((fr & 7) << 4))) = v;
    }
    __syncthreads();
#pragma unroll
    for (int kk = 0; kk < 2; ++kk) {
      int kofs = kk * 64 + lk * 16;
      s16x8 afr[4], bfr[4];
#pragma unroll
      for (int mf = 0; mf < 4; ++mf) {
        int ar = mf * 16 + lr;
        afr[mf] = *reinterpret_cast<const s16x8*>(Alds + ar * 128 + (kofs ^ ((ar & 7) << 4)));
      }
#pragma unroll
      for (int nf = 0; nf < 4; ++nf) {
        int br = w * 64 + nf * 16 + lr;
        bfr[nf] = *reinterpret_cast<const s16x8*>(Blds + br * 128 + (kofs ^ ((br & 7) << 4)));
      }
#pragma unroll
      for (int mf = 0; mf < 4; ++mf)
#pragma unroll
        for (int nf = 0; nf < 4; ++nf)
          acc[mf][nf] = __builtin_amdgcn_mfma_f32_16x16x32_bf16(afr[mf], bfr[nf], acc[mf][nf], 0, 0, 0);
    }
  }
  int tj = blockIdx.x;
#pragma unroll
  for (int mf = 0; mf < 4; ++mf) {
#pragma unroll
    for (int nf = 0; nf < 4; ++nf) {
      int f = w * 64 + nf * 16 + lr;
      int jj = mf * 16 + lk * 4;
      int kc = jj >> 3, sub = (jj >> 2) & 1;
      ushort4 pk;
      pk.x = f2bf(acc[mf][nf][0]);
      pk.y = f2bf(acc[mf][nf][1]);
      pk.z = f2bf(acc[mf][nf][2]);
      pk.w = f2bf(acc[mf][nf][3]);
      *reinterpret_cast<ushort4*>(WhbT + (size_t)tj * 32768 + f * 128 +
                                  ((kc * 16) ^ ((f & 7) << 4)) + sub * 8) = pk;
    }
  }
  float a1v[4], a2v[4];
#pragma unroll
  for (int nf = 0; nf < 4; ++nf) {
    int f = w * 64 + nf * 16 + lr;
    a1v[nf] = a[f];
    a2v[nf] = a[256 + f];
  }
  float* s1l = (float*)lds;
  float* s2l = s1l + 64;
  __syncthreads();
  if (t < 128) s1l[t] = 0.f;
  __syncthreads();
#pragma unroll
  for (int mf = 0; mf < 4; ++mf) {
#pragma unroll
    for (int r = 0; r < 4; ++r) {
      float p1 = 0.f, p2 = 0.f;
#pragma unroll
      for (int nf = 0; nf < 4; ++nf) {
        p1 += acc[mf][nf][r] * a1v[nf];
        p2 += acc[mf][nf][r] * a2v[nf];
      }
      p1 += __shfl_xor(p1, 1); p1 += __shfl_xor(p1, 2);
      p1 += __shfl_xor(p1, 4); p1 += __shfl_xor(p1, 8);
      p2 += __shfl_xor(p2, 1); p2 += __shfl_xor(p2, 2);
      p2 += __shfl_xor(p2, 4); p2 += __shfl_xor(p2, 8);
      if (lr == 0) {
        atomicAdd(&s1l[mf * 16 + lk * 4 + r], p1);
        atomicAdd(&s2l[mf * 16 + lk * 4 + r], p2);
      }
    }
  }
  __syncthreads();
  if (t < 64) {
    s1g[i0 + t] = s1l[t] * LOG2E;
    s2g[i0 + t] = s2l[t] * LOG2E;
  }
}

// ---------------- k3: M=256/block; adj->A-frag regs; B glds dbuf; counted vmcnt ----------------
// 512 thr = 8 waves, each wave owns 32 rows (2 frag-rows). grid (32, 8) = 256 blocks = 1/CU.
// Per tile per wave: 4 B-glds (0 VGPR) + 8 adj reg-loads = 12 VMEM in flight -> vmcnt(12).
// Raw s_barrier only (no vmcnt-0 drains in loop). B LDS reads amortized over 2x rows.
__global__ __launch_bounds__(512, 2) void k3_attn(const float* __restrict__ adj,
                                                  const char* __restrict__ WhbT,
                                                  const float* __restrict__ s1,
                                                  const float* __restrict__ s2,
                                                  float* __restrict__ numw,
                                                  float* __restrict__ denw) {
  __shared__ char lds[2 * 32768 + 4096];   // B dbuf | s2l
  char* Bbase = lds;
  float* s2l = (float*)(lds + 65536);
  int t = threadIdx.x, w = t >> 6, l = t & 63, lr = l & 15, lk = l >> 4;
  int i0 = blockIdx.x * 256;
  int ks = blockIdx.y;
  int jb = ks * JBLK;
  int rowA = i0 + w * 32 + lr;
  int rowB = rowA + 16;
  float s1vA = s1[rowA], s1vB = s1[rowB];
  const float* aArow = adj + (size_t)rowA * N + jb + lk * 8;
  const float* aBrow = adj + (size_t)rowB * N + jb + lk * 8;

  // stage s2 slice (pre-scaled) once: 1024 floats
  *reinterpret_cast<float2*>(&s2l[t * 2]) = *reinterpret_cast<const float2*>(s2 + jb + t * 2);

  f32x4 acc0[16] = {}, acc1[16] = {};
  float dsA = 0.f, dsB = 0.f;

#define STAGE_B(tile, buf)                                                      \
  {                                                                             \
    const char* gB = WhbT + (size_t)(ks * NITER + (tile)) * 32768 + w * 4096;   \
    char* lB = Bbase + (buf) * 32768 + w * 4096;                                \
    _Pragma("unroll") for (int c = 0; c < 4; ++c)                               \
        glds16(gB + c * 1024 + l * 16, lB + c * 1024);                          \
  }
#define LOAD_ADJ(dst, tile)                                                     \
  {                                                                             \
    const float* pa = aArow + (tile) * 64;                                      \
    const float* pb = aBrow + (tile) * 64;                                      \
    dst[0] = *reinterpret_cast<const float4*>(pa);                              \
    dst[1] = *reinterpret_cast<const float4*>(pa + 4);                          \
    dst[2] = *reinterpret_cast<const float4*>(pa + 32);                         \
    dst[3] = *reinterpret_cast<const float4*>(pa + 36);                         \
    dst[4] = *reinterpret_cast<const float4*>(pb);                              \
    dst[5] = *reinterpret_cast<const float4*>(pb + 4);                          \
    dst[6] = *reinterpret_cast<const float4*>(pb + 32);                         \
    dst[7] = *reinterpret_cast<const float4*>(pb + 36);                         \
  }
#define PEL(dst, e, av, sv, dsx)                                                \
  {                                                                             \
    float x = (dst##_s1) + (sv); x = fmaxf(x, 0.2f * x);                        \
    float p = (av) > 0.f ? exp2f(x) : 0.f;                                      \
    unsigned short us = (unsigned short)((__float_as_uint(p) + 0x8000u) >> 16); \
    dsx += bf2f(us); dst[e] = (short)us;                                        \
  }
  // builds one A-frag (8 elems) from two float4 adj chunks + two float4 s2 chunks
#define PFRAG(dst, a0, a1, sv0, sv1, dsx)                                       \
  PEL(dst, 0, a0.x, sv0.x, dsx) PEL(dst, 1, a0.y, sv0.y, dsx)                   \
  PEL(dst, 2, a0.z, sv0.z, dsx) PEL(dst, 3, a0.w, sv0.w, dsx)                   \
  PEL(dst, 4, a1.x, sv1.x, dsx) PEL(dst, 5, a1.y, sv1.y, dsx)                   \
  PEL(dst, 6, a1.z, sv1.z, dsx) PEL(dst, 7, a1.w, sv1.w, dsx)

#define BODY(IT, CUR, NXT)                                                      \
  {                                                                             \
    const int it = (IT);                                                        \
    int cb = it & 1;                                                            \
    if (it + 1 < NITER) {                                                       \
      STAGE_B(it + 1, cb ^ 1);                                                  \
      LOAD_ADJ(NXT, it + 1);                                                    \
      asm volatile("s_waitcnt vmcnt(12)" ::: "memory");                         \
    } else {                                                                    \
      asm volatile("s_waitcnt vmcnt(0)" ::: "memory");                          \
    }                                                                           \
    __builtin_amdgcn_s_barrier();                                               \
    const float* sp = &s2l[it * 64 + lk * 8];                                   \
    float4 sv00 = *reinterpret_cast<const float4*>(sp);                         \
    float4 sv01 = *reinterpret_cast<const float4*>(sp + 4);                     \
    float4 sv10 = *reinterpret_cast<const float4*>(sp + 32);                    \
    float4 sv11 = *reinterpret_cast<const float4*>(sp + 36);                    \
    s16x8 afA0, afA1, afB0, afB1;                                               \
    float afA0_s1 = s1vA, afA1_s1 = s1vA, afB0_s1 = s1vB, afB1_s1 = s1vB;       \
    (void)afA0_s1; (void)afA1_s1; (void)afB0_s1; (void)afB1_s1;                 \
    PFRAG(afA0, CUR[0], CUR[1], sv00, sv01, dsA)                                \
    PFRAG(afA1, CUR[2], CUR[3], sv10, sv11, dsA)                                \
    PFRAG(afB0, CUR[4], CUR[5], sv00, sv01, dsB)                                \
    PFRAG(afB1, CUR[6], CUR[7], sv10, sv11, dsB)                                \
    const char* Bt = Bbase + cb * 32768;                                        \
    _Pragma("unroll") for (int kk = 0; kk < 2; ++kk) {                          \
      int kofs = kk * 64 + lk * 16;                                             \
      s16x8 aA = kk ? afA1 : afA0;                                              \
      s16x8 aB = kk ? afB1 : afB0;                                              \
      _Pragma("unroll") for (int nf = 0; nf < 16; ++nf) {                       \
        int br = nf * 16 + lr;                                                  \
        s16x8 bfr = *reinterpret_cast<const s16x8*>(                            \
            Bt + br * 128 + (kofs ^ ((br & 7) << 4)));                          \
        acc0[nf] = __builtin_amdgcn_mfma_f32_16x16x32_bf16(aA, bfr, acc0[nf], 0, 0, 0); \
        acc1[nf] = __builtin_amdgcn_mfma_f32_16x16x32_bf16(aB, bfr, acc1[nf], 0, 0, 0); \
      }                                                                         \
    }                                                                           \
    asm volatile("s_waitcnt lgkmcnt(0)" ::: "memory");                          \
    __builtin_amdgcn_s_barrier();                                               \
  }

  float4 ajP[8], ajQ[8];
  STAGE_B(0, 0);
  LOAD_ADJ(ajP, 0);
  __syncthreads();   // prologue drain (once): s2l + B(0) + adj(0)

  for (int it2 = 0; it2 < NITER / 2; ++it2) {
    BODY(2 * it2, ajP, ajQ);
    BODY(2 * it2 + 1, ajQ, ajP);
  }
#undef BODY
#undef PFRAG
#undef PEL
#undef LOAD_ADJ
#undef STAGE_B

  // denominators: lane covers a disjoint lk-partition of cols; reduce across lk
  dsA += __shfl_xor(dsA, 16); dsA += __shfl_xor(dsA, 32);
  dsB += __shfl_xor(dsB, 16); dsB += __shfl_xor(dsB, 32);
  if (l < 16) {
    denw[(size_t)ks * N + rowA] = dsA;
    denw[(size_t)ks * N + rowB] = dsB;
  }
  // numerator partials
  float* nump = numw + (size_t)ks * N * F;
#pragma unroll
  for (int nf = 0; nf < 16; ++nf) {
#pragma unroll
    for (int rr = 0; rr < 4; ++rr) {
      int irow = i0 + w * 32 + lk * 4 + rr;
      nump[(size_t)irow * F + nf * 16 + lr] = acc0[nf][rr];
      nump[(size_t)(irow + 16) * F + nf * 16 + lr] = acc1[nf][rr];
    }
  }
}

// ---------------- k4: combine K-splits, divide, elu (float4) ----------------
__global__ __launch_bounds__(256) void k4_fin(const float* __restrict__ numw,
                                              const float* __restrict__ denw,
                                              float* __restrict__ out) {
  int idx = (blockIdx.x * 256 + threadIdx.x) * 4;
  int i = idx >> 8;
  float4 sn = {0.f, 0.f, 0.f, 0.f};
  float sd = 0.f;
#pragma unroll
  for (int ksp = 0; ksp < KSPLIT; ++ksp) {
    float4 v = *reinterpret_cast<const float4*>(numw + (size_t)ksp * N * F + idx);
    sn.x += v.x; sn.y += v.y; sn.z += v.z; sn.w += v.w;
    sd += denw[(size_t)ksp * N + i];
  }
  float r = 1.f / sd;
  float4 o;
  float hp;
  hp = sn.x * r; o.x = hp > 0.f ? hp : (__expf(hp) - 1.f);
  hp = sn.y * r; o.y = hp > 0.f ? hp : (__expf(hp) - 1.f);
  hp = sn.z * r; o.z = hp > 0.f ? hp : (__expf(hp) - 1.f);
  hp = sn.w * r; o.w = hp > 0.f ? hp : (__expf(hp) - 1.f);
  *reinterpret_cast<float4*>(out + idx) = o;
}

extern "C" void kernel_launch(void* const* d_in, const int* in_sizes, int n_in,
                              void* d_out, int out_size, void* d_ws, size_t ws_size,
                              hipStream_t stream) {
  const float* h   = (const float*)d_in[0];
  const float* adj = (const float*)d_in[1];
  const float* W   = (const float*)d_in[2];
  const float* a   = (const float*)d_in[3];
  float* out = (float*)d_out;

  char* ws = (char*)d_ws;
  size_t o = 0;
  char* WhbT           = ws + o;                    o += (size_t)4 * 1024 * 1024;    // tiled
  float* s1            = (float*)(ws + o);          o += 32768;
  float* s2            = (float*)(ws + o);          o += 32768;
  float* denw          = (float*)(ws + o);          o += (size_t)KSPLIT * N * 4;     // 256 KB
  unsigned short* Wt   = (unsigned short*)(ws + o); o += 131072;
  float* numw          = (float*)(ws + o);          o += (size_t)KSPLIT * N * F * 4; // 64 MB

  hipLaunchKernelGGL(k0_wt, dim3(256), dim3(256), 0, stream, W, Wt);
  hipLaunchKernelGGL(k1_wh, dim3(N / 64), dim3(256), 0, stream, h, Wt, a, WhbT, s1, s2);
  hipLaunchKernelGGL(k3_attn, dim3(N / 256, KSPLIT), dim3(512), 0, stream,
                     adj, WhbT, s1, s2, numw, denw);
  hipLaunchKernelGGL(k4_fin, dim3(N * F / 1024), dim3(256), 0, stream, numw, denw, out);
}

// Round 11
// 198.044 us; speedup vs baseline: 1.6510x; 1.6510x over previous
//
#include <hip/hip_runtime.h>
#include <hip/hip_bf16.h>

#define N 8192
#define F 256
#define KSPLIT 8
#define JBLK (N / KSPLIT)    // 1024 cols per k3 block
#define NITER (JBLK / 64)    // 16 j-tiles of 64
#define LOG2E 1.4426950408889634f

using s16x8 = __attribute__((ext_vector_type(8))) short;
using f32x4 = __attribute__((ext_vector_type(4))) float;

static __device__ __forceinline__ unsigned short f2bf(float f) {
  unsigned int u = __float_as_uint(f);
  unsigned int r = u + 0x7fffu + ((u >> 16) & 1u);   // RNE
  return (unsigned short)(r >> 16);
}
static __device__ __forceinline__ float bf2f(unsigned short u) {
  return __uint_as_float(((unsigned int)u) << 16);
}
static __device__ __forceinline__ void glds16(const void* g, void* l) {
  __builtin_amdgcn_global_load_lds(
      (const __attribute__((address_space(1))) unsigned int*)g,
      (__attribute__((address_space(3))) unsigned int*)l, 16, 0, 0);
}

// ---------------- k0: Wt[f][k] = bf16(W[k][f]) ----------------
__global__ __launch_bounds__(256) void k0_wt(const float* __restrict__ W,
                                             unsigned short* __restrict__ Wt) {
  int k = blockIdx.x;
  int f = threadIdx.x;
  Wt[f * 256 + k] = f2bf(W[k * 256 + f]);
}

// ---------------- k1: Wh GEMM -> tiled/swizzled WhbT + fused s1,s2 (pre-scaled by log2e) ----
__global__ __launch_bounds__(256) void k1_wh(const float* __restrict__ h,
                                             const unsigned short* __restrict__ Wt,
                                             const float* __restrict__ a,
                                             char* __restrict__ WhbT,
                                             float* __restrict__ s1g,
                                             float* __restrict__ s2g) {
  __shared__ char lds[8192 + 32768];
  char* Alds = lds;
  char* Blds = lds + 8192;
  int t = threadIdx.x;
  int i0 = blockIdx.x * 64;
  int l = t & 63, w = t >> 6;
  int lr = l & 15, lk = l >> 4;
  f32x4 acc[4][4] = {};
  for (int kt = 0; kt < 4; ++kt) {
    int k0 = kt * 64;
    if (kt) __syncthreads();
#pragma unroll
    for (int c = 0; c < 4; ++c) {
      int flat = c * 256 + t;
      int i = flat >> 4, jc = flat & 15;
      float4 v = *reinterpret_cast<const float4*>(h + (size_t)(i0 + i) * 256 + k0 + jc * 4);
      ushort4 pk;
      pk.x = f2bf(v.x); pk.y = f2bf(v.y); pk.z = f2bf(v.z); pk.w = f2bf(v.w);
      *reinterpret_cast<ushort4*>(Alds + i * 128 + ((jc * 8) ^ ((i & 7) << 4))) = pk;
    }
#pragma unroll
    for (int c = 0; c < 8; ++c) {
      int idx = c * 256 + t;
      int fr = idx >> 3, kc = idx & 7;
      uint4 v = *reinterpret_cast<const uint4*>(Wt + fr * 256 + k0 + kc * 8);
      *reinterpret_cast<uint4*>(Blds + fr * 128 + ((kc * 16) ^ ((fr & 7) << 4))) = v;
    }
    __syncthreads();
#pragma unroll
    for (int kk = 0; kk < 2; ++kk) {
      int kofs = kk * 64 + lk * 16;
      s16x8 afr[4], bfr[4];
#pragma unroll
      for (int mf = 0; mf < 4; ++mf) {
        int ar = mf * 16 + lr;
        afr[mf] = *reinterpret_cast<const s16x8*>(Alds + ar * 128 + (kofs ^ ((ar & 7) << 4)));
      }
#pragma unroll
      for (int nf = 0; nf < 4; ++nf) {
        int br = w * 64 + nf * 16 + lr;
        bfr[nf] = *reinterpret_cast<const s16x8*>(Blds + br * 128 + (kofs ^ ((br & 7) << 4)));
      }
#pragma unroll
      for (int mf = 0; mf < 4; ++mf)
#pragma unroll
        for (int nf = 0; nf < 4; ++nf)
          acc[mf][nf] = __builtin_amdgcn_mfma_f32_16x16x32_bf16(afr[mf], bfr[nf], acc[mf][nf], 0, 0, 0);
    }
  }
  int tj = blockIdx.x;
#pragma unroll
  for (int mf = 0; mf < 4; ++mf) {
#pragma unroll
    for (int nf = 0; nf < 4; ++nf) {
      int f = w * 64 + nf * 16 + lr;
      int jj = mf * 16 + lk * 4;
      int kc = jj >> 3, sub = (jj >> 2) & 1;
      ushort4 pk;
      pk.x = f2bf(acc[mf][nf][0]);
      pk.y = f2bf(acc[mf][nf][1]);
      pk.z = f2bf(acc[mf][nf][2]);
      pk.w = f2bf(acc[mf][nf][3]);
      *reinterpret_cast<ushort4*>(WhbT + (size_t)tj * 32768 + f * 128 +
                                  ((kc * 16) ^ ((f & 7) << 4)) + sub * 8) = pk;
    }
  }
  float a1v[4], a2v[4];
#pragma unroll
  for (int nf = 0; nf < 4; ++nf) {
    int f = w * 64 + nf * 16 + lr;
    a1v[nf] = a[f];
    a2v[nf] = a[256 + f];
  }
  float* s1l = (float*)lds;
  float* s2l = s1l + 64;
  __syncthreads();
  if (t < 128) s1l[t] = 0.f;
  __syncthreads();
#pragma unroll
  for (int mf = 0; mf < 4; ++mf) {
#pragma unroll
    for (int r = 0; r < 4; ++r) {
      float p1 = 0.f, p2 = 0.f;
#pragma unroll
      for (int nf = 0; nf < 4; ++nf) {
        p1 += acc[mf][nf][r] * a1v[nf];
        p2 += acc[mf][nf][r] * a2v[nf];
      }
      p1 += __shfl_xor(p1, 1); p1 += __shfl_xor(p1, 2);
      p1 += __shfl_xor(p1, 4); p1 += __shfl_xor(p1, 8);
      p2 += __shfl_xor(p2, 1); p2 += __shfl_xor(p2, 2);
      p2 += __shfl_xor(p2, 4); p2 += __shfl_xor(p2, 8);
      if (lr == 0) {
        atomicAdd(&s1l[mf * 16 + lk * 4 + r], p1);
        atomicAdd(&s2l[mf * 16 + lk * 4 + r], p2);
      }
    }
  }
  __syncthreads();
  if (t < 64) {
    s1g[i0 + t] = s1l[t] * LOG2E;
    s2g[i0 + t] = s2l[t] * LOG2E;
  }
}

// ---------------- k3: M=128, F-split waves (4M x 2F); adj->regs; B glds dbuf; counted vmcnt ----
// 512 thr = 8 waves: wave(mg=w&3, fg=w>>2) owns rows mg*32..+31 (2 frag-rows) x F-cols fg*128..+127.
// grid (64, 8) = 512 blocks, LDS 68KB -> 2 blocks/CU (16 waves) for cross-block overlap.
// Per iter per wave: 4 B-glds + 8 adj reg-loads = 12 VMEM -> s_waitcnt vmcnt(12) (counted).
__global__ __launch_bounds__(512) void k3_attn(const float* __restrict__ adj,
                                               const char* __restrict__ WhbT,
                                               const float* __restrict__ s1,
                                               const float* __restrict__ s2,
                                               float* __restrict__ numw,
                                               float* __restrict__ denw) {
  __shared__ char lds[2 * 32768 + 4096];   // B dbuf | s2l
  char* Bbase = lds;
  float* s2l = (float*)(lds + 65536);
  int t = threadIdx.x, w = t >> 6, l = t & 63, lr = l & 15, lk = l >> 4;
  int mg = w & 3, fg = w >> 2;
  int i0 = blockIdx.x * 128;
  int ks = blockIdx.y;
  int jb = ks * JBLK;
  int rowA = i0 + mg * 32 + lr;
  int rowB = rowA + 16;
  float s1vA = s1[rowA], s1vB = s1[rowB];
  const float* aArow = adj + (size_t)rowA * N + jb + lk * 8;
  const float* aBrow = adj + (size_t)rowB * N + jb + lk * 8;

  // stage s2 slice (pre-scaled) once: 1024 floats
  *reinterpret_cast<float2*>(&s2l[t * 2]) = *reinterpret_cast<const float2*>(s2 + jb + t * 2);

  f32x4 acc0[8] = {}, acc1[8] = {};
  float dsA = 0.f, dsB = 0.f;

#define STAGE_B(tile, buf)                                                      \
  {                                                                             \
    const char* gB = WhbT + (size_t)(ks * NITER + (tile)) * 32768 + w * 4096;   \
    char* lB = Bbase + (buf) * 32768 + w * 4096;                                \
    _Pragma("unroll") for (int c = 0; c < 4; ++c)                               \
        glds16(gB + c * 1024 + l * 16, lB + c * 1024);                          \
  }
#define LOAD_ADJ(dst, tile)                                                     \
  {                                                                             \
    const float* pa = aArow + (tile) * 64;                                      \
    const float* pb = aBrow + (tile) * 64;                                      \
    dst[0] = *reinterpret_cast<const float4*>(pa);                              \
    dst[1] = *reinterpret_cast<const float4*>(pa + 4);                          \
    dst[2] = *reinterpret_cast<const float4*>(pa + 32);                         \
    dst[3] = *reinterpret_cast<const float4*>(pa + 36);                         \
    dst[4] = *reinterpret_cast<const float4*>(pb);                              \
    dst[5] = *reinterpret_cast<const float4*>(pb + 4);                          \
    dst[6] = *reinterpret_cast<const float4*>(pb + 32);                         \
    dst[7] = *reinterpret_cast<const float4*>(pb + 36);                         \
  }
#define PEL(dst, e, av, sv, s1p, dsx)                                           \
  {                                                                             \
    float x = (s1p) + (sv); x = fmaxf(x, 0.2f * x);                             \
    float p = (av) > 0.f ? exp2f(x) : 0.f;                                      \
    unsigned short us = (unsigned short)((__float_as_uint(p) + 0x8000u) >> 16); \
    dsx += bf2f(us); dst[e] = (short)us;                                        \
  }
#define PFRAG(dst, a0, a1, sv0, sv1, s1p, dsx)                                  \
  PEL(dst, 0, a0.x, sv0.x, s1p, dsx) PEL(dst, 1, a0.y, sv0.y, s1p, dsx)         \
  PEL(dst, 2, a0.z, sv0.z, s1p, dsx) PEL(dst, 3, a0.w, sv0.w, s1p, dsx)         \
  PEL(dst, 4, a1.x, sv1.x, s1p, dsx) PEL(dst, 5, a1.y, sv1.y, s1p, dsx)         \
  PEL(dst, 6, a1.z, sv1.z, s1p, dsx) PEL(dst, 7, a1.w, sv1.w, s1p, dsx)

#define BODY(IT, CUR, NXT)                                                      \
  {                                                                             \
    const int it = (IT);                                                        \
    int cb = it & 1;                                                            \
    if (it + 1 < NITER) {                                                       \
      STAGE_B(it + 1, cb ^ 1);                                                  \
      LOAD_ADJ(NXT, it + 1);                                                    \
      asm volatile("s_waitcnt vmcnt(12)" ::: "memory");                         \
    } else {                                                                    \
      asm volatile("s_waitcnt vmcnt(0)" ::: "memory");                          \
    }                                                                           \
    __builtin_amdgcn_s_barrier();                                               \
    const float* sp = &s2l[it * 64 + lk * 8];                                   \
    float4 sv00 = *reinterpret_cast<const float4*>(sp);                         \
    float4 sv01 = *reinterpret_cast<const float4*>(sp + 4);                     \
    float4 sv10 = *reinterpret_cast<const float4*>(sp + 32);                    \
    float4 sv11 = *reinterpret_cast<const float4*>(sp + 36);                    \
    s16x8 afA0, afA1, afB0, afB1;                                               \
    PFRAG(afA0, CUR[0], CUR[1], sv00, sv01, s1vA, dsA)                          \
    PFRAG(afA1, CUR[2], CUR[3], sv10, sv11, s1vA, dsA)                          \
    PFRAG(afB0, CUR[4], CUR[5], sv00, sv01, s1vB, dsB)                          \
    PFRAG(afB1, CUR[6], CUR[7], sv10, sv11, s1vB, dsB)                          \
    const char* Bt = Bbase + cb * 32768;                                        \
    _Pragma("unroll") for (int kk = 0; kk < 2; ++kk) {                          \
      int kofs = kk * 64 + lk * 16;                                             \
      s16x8 aA = kk ? afA1 : afA0;                                              \
      s16x8 aB = kk ? afB1 : afB0;                                              \
      _Pragma("unroll") for (int nf = 0; nf < 8; ++nf) {                        \
        int br = fg * 128 + nf * 16 + lr;                                       \
        s16x8 bfr = *reinterpret_cast<const s16x8*>(                            \
            Bt + br * 128 + (kofs ^ ((br & 7) << 4)));                          \
        acc0[nf] = __builtin_amdgcn_mfma_f32_16x16x32_bf16(aA, bfr, acc0[nf], 0, 0, 0); \
        acc1[nf] = __builtin_amdgcn_mfma_f32_16x16x32_bf16(aB, bfr, acc1[nf], 0, 0, 0); \
      }                                                                         \
    }                                                                           \
    asm volatile("s_waitcnt lgkmcnt(0)" ::: "memory");                          \
    __builtin_amdgcn_s_barrier();                                               \
  }

  float4 ajP[8], ajQ[8];
  STAGE_B(0, 0);
  LOAD_ADJ(ajP, 0);
  __syncthreads();   // prologue drain (once): s2l + B(0) + adj(0)

  for (int it2 = 0; it2 < NITER / 2; ++it2) {
    BODY(2 * it2, ajP, ajQ);
    BODY(2 * it2 + 1, ajQ, ajP);
  }
#undef BODY
#undef PFRAG
#undef PEL
#undef LOAD_ADJ
#undef STAGE_B

  // denominators: both fg-waves computed identical sums; only fg==0 writes
  dsA += __shfl_xor(dsA, 16); dsA += __shfl_xor(dsA, 32);
  dsB += __shfl_xor(dsB, 16); dsB += __shfl_xor(dsB, 32);
  if (fg == 0 && l < 16) {
    denw[(size_t)ks * N + rowA] = dsA;
    denw[(size_t)ks * N + rowB] = dsB;
  }
  // numerator partials
  float* nump = numw + (size_t)ks * N * F;
#pragma unroll
  for (int nf = 0; nf < 8; ++nf) {
#pragma unroll
    for (int rr = 0; rr < 4; ++rr) {
      int irow = i0 + mg * 32 + lk * 4 + rr;
      int col = fg * 128 + nf * 16 + lr;
      nump[(size_t)irow * F + col] = acc0[nf][rr];
      nump[(size_t)(irow + 16) * F + col] = acc1[nf][rr];
    }
  }
}

// ---------------- k4: combine K-splits, divide, elu (float4) ----------------
__global__ __launch_bounds__(256) void k4_fin(const float* __restrict__ numw,
                                              const float* __restrict__ denw,
                                              float* __restrict__ out) {
  int idx = (blockIdx.x * 256 + threadIdx.x) * 4;
  int i = idx >> 8;
  float4 sn = {0.f, 0.f, 0.f, 0.f};
  float sd = 0.f;
#pragma unroll
  for (int ksp = 0; ksp < KSPLIT; ++ksp) {
    float4 v = *reinterpret_cast<const float4*>(numw + (size_t)ksp * N * F + idx);
    sn.x += v.x; sn.y += v.y; sn.z += v.z; sn.w += v.w;
    sd += denw[(size_t)ksp * N + i];
  }
  float r = 1.f / sd;
  float4 o;
  float hp;
  hp = sn.x * r; o.x = hp > 0.f ? hp : (__expf(hp) - 1.f);
  hp = sn.y * r; o.y = hp > 0.f ? hp : (__expf(hp) - 1.f);
  hp = sn.z * r; o.z = hp > 0.f ? hp : (__expf(hp) - 1.f);
  hp = sn.w * r; o.w = hp > 0.f ? hp : (__expf(hp) - 1.f);
  *reinterpret_cast<float4*>(out + idx) = o;
}

extern "C" void kernel_launch(void* const* d_in, const int* in_sizes, int n_in,
                              void* d_out, int out_size, void* d_ws, size_t ws_size,
                              hipStream_t stream) {
  const float* h   = (const float*)d_in[0];
  const float* adj = (const float*)d_in[1];
  const float* W   = (const float*)d_in[2];
  const float* a   = (const float*)d_in[3];
  float* out = (float*)d_out;

  char* ws = (char*)d_ws;
  size_t o = 0;
  char* WhbT           = ws + o;                    o += (size_t)4 * 1024 * 1024;    // tiled
  float* s1            = (float*)(ws + o);          o += 32768;
  float* s2            = (float*)(ws + o);          o += 32768;
  float* denw          = (float*)(ws + o);          o += (size_t)KSPLIT * N * 4;     // 256 KB
  unsigned short* Wt   = (unsigned short*)(ws + o); o += 131072;
  float* numw          = (float*)(ws + o);          o += (size_t)KSPLIT * N * F * 4; // 64 MB

  hipLaunchKernelGGL(k0_wt, dim3(256), dim3(256), 0, stream, W, Wt);
  hipLaunchKernelGGL(k1_wh, dim3(N / 64), dim3(256), 0, stream, h, Wt, a, WhbT, s1, s2);
  hipLaunchKernelGGL(k3_attn, dim3(N / 128, KSPLIT), dim3(512), 0, stream,
                     adj, WhbT, s1, s2, numw, denw);
  hipLaunchKernelGGL(k4_fin, dim3(N * F / 1024), dim3(256), 0, stream, numw, denw, out);
}

// Round 12
// 133.885 us; speedup vs baseline: 2.4422x; 1.4792x over previous
//
#include <hip/hip_runtime.h>
#include <hip/hip_bf16.h>

#define N 8192
#define F 256
#define KSPLIT 8
#define JBLK (N / KSPLIT)    // 1024 cols per k3 block
#define NITER (JBLK / 32)    // 32 j-tiles of 32 cols
#define LOG2E 1.4426950408889634f

using s16x8 = __attribute__((ext_vector_type(8))) short;
using f32x4 = __attribute__((ext_vector_type(4))) float;

static __device__ __forceinline__ unsigned short f2bf(float f) {
  unsigned int u = __float_as_uint(f);
  unsigned int r = u + 0x7fffu + ((u >> 16) & 1u);   // RNE
  return (unsigned short)(r >> 16);
}
static __device__ __forceinline__ float bf2f(unsigned short u) {
  return __uint_as_float(((unsigned int)u) << 16);
}
static __device__ __forceinline__ void glds16(const void* g, void* l) {
  __builtin_amdgcn_global_load_lds(
      (const __attribute__((address_space(1))) unsigned int*)g,
      (__attribute__((address_space(3))) unsigned int*)l, 16, 0, 0);
}

// ---------------- k0: Wt[f][k] = bf16(W[k][f]) ----------------
__global__ __launch_bounds__(256) void k0_wt(const float* __restrict__ W,
                                             unsigned short* __restrict__ Wt) {
  int k = blockIdx.x;
  int f = threadIdx.x;
  Wt[f * 256 + k] = f2bf(W[k * 256 + f]);
}

// ---------------- k1: Wh GEMM -> 32-col tiled/swizzled WhbT + fused s1,s2 (pre-scaled) ----
// WhbT layout: tile tj (32 j's, 16KB): byte = tj*16384 + (f>>1)*128
//   + (((((f&1)<<2) + g) ^ ((f>>1)&7)) * 16) + sub*8, where g=(j&31)>>3, sub=(j>>2)&1.
// Tile content == k3's LDS image (linear glds copy); B ds_reads ~2-way conflict-free.
__global__ __launch_bounds__(256) void k1_wh(const float* __restrict__ h,
                                             const unsigned short* __restrict__ Wt,
                                             const float* __restrict__ a,
                                             char* __restrict__ WhbT,
                                             float* __restrict__ s1g,
                                             float* __restrict__ s2g) {
  __shared__ char lds[8192 + 32768];
  char* Alds = lds;
  char* Blds = lds + 8192;
  int t = threadIdx.x;
  int i0 = blockIdx.x * 64;
  int l = t & 63, w = t >> 6;
  int lr = l & 15, lk = l >> 4;
  f32x4 acc[4][4] = {};
  for (int kt = 0; kt < 4; ++kt) {
    int k0 = kt * 64;
    if (kt) __syncthreads();
#pragma unroll
    for (int c = 0; c < 4; ++c) {
      int flat = c * 256 + t;
      int i = flat >> 4, jc = flat & 15;
      float4 v = *reinterpret_cast<const float4*>(h + (size_t)(i0 + i) * 256 + k0 + jc * 4);
      ushort4 pk;
      pk.x = f2bf(v.x); pk.y = f2bf(v.y); pk.z = f2bf(v.z); pk.w = f2bf(v.w);
      *reinterpret_cast<ushort4*>(Alds + i * 128 + ((jc * 8) ^ ((i & 7) << 4))) = pk;
    }
#pragma unroll
    for (int c = 0; c < 8; ++c) {
      int idx = c * 256 + t;
      int fr = idx >> 3, kc = idx & 7;
      uint4 v = *reinterpret_cast<const uint4*>(Wt + fr * 256 + k0 + kc * 8);
      *reinterpret_cast<uint4*>(Blds + fr * 128 + ((kc * 16) ^ ((fr & 7) << 4))) = v;
    }
    __syncthreads();
#pragma unroll
    for (int kk = 0; kk < 2; ++kk) {
      int kofs = kk * 64 + lk * 16;
      s16x8 afr[4], bfr[4];
#pragma unroll
      for (int mf = 0; mf < 4; ++mf) {
        int ar = mf * 16 + lr;
        afr[mf] = *reinterpret_cast<const s16x8*>(Alds + ar * 128 + (kofs ^ ((ar & 7) << 4)));
      }
#pragma unroll
      for (int nf = 0; nf < 4; ++nf) {
        int br = w * 64 + nf * 16 + lr;
        bfr[nf] = *reinterpret_cast<const s16x8*>(Blds + br * 128 + (kofs ^ ((br & 7) << 4)));
      }
#pragma unroll
      for (int mf = 0; mf < 4; ++mf)
#pragma unroll
        for (int nf = 0; nf < 4; ++nf)
          acc[mf][nf] = __builtin_amdgcn_mfma_f32_16x16x32_bf16(afr[mf], bfr[nf], acc[mf][nf], 0, 0, 0);
    }
  }
  // epilogue: store in k3-ready 32-col tiled/swizzled layout
#pragma unroll
  for (int mf = 0; mf < 4; ++mf) {
#pragma unroll
    for (int nf = 0; nf < 4; ++nf) {
      int f = w * 64 + nf * 16 + lr;
      int tj32 = blockIdx.x * 2 + (mf >> 1);
      int g = ((mf & 1) << 1) + (lk >> 1);
      int sub = lk & 1;
      int fp = f >> 1;
      int u = ((((f & 1) << 2) + g) ^ (fp & 7));
      ushort4 pk;
      pk.x = f2bf(acc[mf][nf][0]);
      pk.y = f2bf(acc[mf][nf][1]);
      pk.z = f2bf(acc[mf][nf][2]);
      pk.w = f2bf(acc[mf][nf][3]);
      *reinterpret_cast<ushort4*>(WhbT + (size_t)tj32 * 16384 + fp * 128 + u * 16 + sub * 8) = pk;
    }
  }
  // fused s1/s2 from f32 accumulators
  float a1v[4], a2v[4];
#pragma unroll
  for (int nf = 0; nf < 4; ++nf) {
    int f = w * 64 + nf * 16 + lr;
    a1v[nf] = a[f];
    a2v[nf] = a[256 + f];
  }
  float* s1l = (float*)lds;
  float* s2l = s1l + 64;
  __syncthreads();
  if (t < 128) s1l[t] = 0.f;
  __syncthreads();
#pragma unroll
  for (int mf = 0; mf < 4; ++mf) {
#pragma unroll
    for (int r = 0; r < 4; ++r) {
      float p1 = 0.f, p2 = 0.f;
#pragma unroll
      for (int nf = 0; nf < 4; ++nf) {
        p1 += acc[mf][nf][r] * a1v[nf];
        p2 += acc[mf][nf][r] * a2v[nf];
      }
      p1 += __shfl_xor(p1, 1); p1 += __shfl_xor(p1, 2);
      p1 += __shfl_xor(p1, 4); p1 += __shfl_xor(p1, 8);
      p2 += __shfl_xor(p2, 1); p2 += __shfl_xor(p2, 2);
      p2 += __shfl_xor(p2, 4); p2 += __shfl_xor(p2, 8);
      if (lr == 0) {
        atomicAdd(&s1l[mf * 16 + lk * 4 + r], p1);
        atomicAdd(&s2l[mf * 16 + lk * 4 + r], p2);
      }
    }
  }
  __syncthreads();
  if (t < 64) {
    s1g[i0 + t] = s1l[t] * LOG2E;
    s2g[i0 + t] = s2l[t] * LOG2E;
  }
}

// ---------------- k3: 32-col tiles; adj+B glds dbuf; counted vmcnt; 2 blocks/CU ----------------
// 512 thr = 8 waves x 16 rows (M=128); grid (64, 8) = 512 blocks; LDS 68KB -> 2 blocks/CU.
// Per iter per wave: 2 adj-glds + 2 B-glds = 4 VMEM -> s_waitcnt vmcnt(4) (counted, never 0 in loop).
// adj LDS image [16 rows][8 granules], granule swizzled g^(r&7) via pre-swizzled glds source.
__global__ __launch_bounds__(512) void k3_attn(const float* __restrict__ adj,
                                               const char* __restrict__ WhbT,
                                               const float* __restrict__ s1,
                                               const float* __restrict__ s2,
                                               float* __restrict__ numw,
                                               float* __restrict__ denw) {
  __shared__ char lds[2 * 16384 + 2 * 16384 + 4096];   // adj dbuf | B dbuf | s2l
  char* Abase = lds;
  char* Bbase = lds + 32768;
  float* s2l = (float*)(lds + 65536);
  int t = threadIdx.x, w = t >> 6, l = t & 63, lr = l & 15, lk = l >> 4;
  int i0 = blockIdx.x * 128;
  int ks = blockIdx.y;
  int jb = ks * JBLK;
  int row = i0 + w * 16 + lr;
  float s1v = s1[row];

  // stage s2 slice (pre-scaled by log2e) once: 1024 floats
  *reinterpret_cast<float2*>(&s2l[t * 2]) = *reinterpret_cast<const float2*>(s2 + jb + t * 2);

  f32x4 acc[16] = {};
  float ds = 0.f;

#define STAGE(tile, buf)                                                        \
  {                                                                             \
    const char* gB = WhbT + (size_t)(ks * NITER + (tile)) * 16384 + w * 2048;   \
    char* lB = Bbase + (buf) * 16384 + w * 2048;                                \
    _Pragma("unroll") for (int c = 0; c < 2; ++c)                               \
        glds16(gB + c * 1024 + l * 16, lB + c * 1024);                          \
    char* lA = Abase + (buf) * 16384 + w * 2048;                                \
    _Pragma("unroll") for (int c = 0; c < 2; ++c) {                             \
      int lr8 = c * 8 + (l >> 3);                                               \
      const float* srcA = adj + (size_t)(i0 + w * 16 + lr8) * N + jb +          \
                          (tile) * 32 + (((l & 7) ^ (lr8 & 7)) << 2);           \
      glds16(srcA, lA + c * 1024);                                              \
    }                                                                           \
  }

  STAGE(0, 0);
  __syncthreads();   // prologue drain (once): s2l + tile 0

  for (int it = 0; it < NITER; ++it) {
    int cb = it & 1;
    if (it + 1 < NITER) {
      STAGE(it + 1, cb ^ 1);
      asm volatile("s_waitcnt vmcnt(4)" ::: "memory");   // tile it landed; it+1 in flight
    } else {
      asm volatile("s_waitcnt vmcnt(0)" ::: "memory");
    }
    __builtin_amdgcn_s_barrier();                        // tile it fully staged

    // ---- adj -> P -> A-fragment (one k-granule pair per lane) ----
    const char* At = Abase + cb * 16384 + w * 2048 + lr * 128;
    f32x4 av0 = *reinterpret_cast<const f32x4*>(At + (((lk << 1) ^ (lr & 7)) << 4));
    f32x4 av1 = *reinterpret_cast<const f32x4*>(At + ((((lk << 1) | 1) ^ (lr & 7)) << 4));
    const float* sp = &s2l[it * 32 + lk * 8];
    float4 sv0 = *reinterpret_cast<const float4*>(sp);
    float4 sv1 = *reinterpret_cast<const float4*>(sp + 4);
    s16x8 afr;
#define PEL(e, av, sv)                                                          \
    {                                                                           \
      float x = s1v + (sv); x = fmaxf(x, 0.2f * x);                             \
      float p = (av) > 0.f ? exp2f(x) : 0.f;                                    \
      unsigned short us = (unsigned short)((__float_as_uint(p) + 0x8000u) >> 16); \
      ds += bf2f(us); afr[e] = (short)us;                                       \
    }
    PEL(0, av0[0], sv0.x) PEL(1, av0[1], sv0.y) PEL(2, av0[2], sv0.z) PEL(3, av0[3], sv0.w)
    PEL(4, av1[0], sv1.x) PEL(5, av1[1], sv1.y) PEL(6, av1[2], sv1.z) PEL(7, av1[3], sv1.w)
#undef PEL

    // ---- MFMA: 16 nf, single k-step (k=32) ----
    const char* Bt = Bbase + cb * 16384;
#pragma unroll
    for (int nf = 0; nf < 16; ++nf) {
      int br = nf * 16 + lr;
      int fp = br >> 1;
      int u = ((((br & 1) << 2) + lk) ^ (fp & 7));
      s16x8 bfr = *reinterpret_cast<const s16x8*>(Bt + fp * 128 + u * 16);
      acc[nf] = __builtin_amdgcn_mfma_f32_16x16x32_bf16(afr, bfr, acc[nf], 0, 0, 0);
    }
    asm volatile("s_waitcnt lgkmcnt(0)" ::: "memory");
    __builtin_amdgcn_s_barrier();                        // reads done; buf may be overwritten
  }
#undef STAGE

  // denominator: reduce across lk (each lk covers a disjoint 8-col slice)
  ds += __shfl_xor(ds, 16);
  ds += __shfl_xor(ds, 32);
  if (l < 16) denw[(size_t)ks * N + row] = ds;

  // numerator partials
  float* nump = numw + (size_t)ks * N * F;
#pragma unroll
  for (int nf = 0; nf < 16; ++nf) {
#pragma unroll
    for (int rr = 0; rr < 4; ++rr) {
      nump[(size_t)(i0 + w * 16 + lk * 4 + rr) * F + nf * 16 + lr] = acc[nf][rr];
    }
  }
}

// ---------------- k4: combine K-splits, divide, elu (float4) ----------------
__global__ __launch_bounds__(256) void k4_fin(const float* __restrict__ numw,
                                              const float* __restrict__ denw,
                                              float* __restrict__ out) {
  int idx = (blockIdx.x * 256 + threadIdx.x) * 4;
  int i = idx >> 8;
  float4 sn = {0.f, 0.f, 0.f, 0.f};
  float sd = 0.f;
#pragma unroll
  for (int ksp = 0; ksp < KSPLIT; ++ksp) {
    float4 v = *reinterpret_cast<const float4*>(numw + (size_t)ksp * N * F + idx);
    sn.x += v.x; sn.y += v.y; sn.z += v.z; sn.w += v.w;
    sd += denw[(size_t)ksp * N + i];
  }
  float r = 1.f / sd;
  float4 o;
  float hp;
  hp = sn.x * r; o.x = hp > 0.f ? hp : (__expf(hp) - 1.f);
  hp = sn.y * r; o.y = hp > 0.f ? hp : (__expf(hp) - 1.f);
  hp = sn.z * r; o.z = hp > 0.f ? hp : (__expf(hp) - 1.f);
  hp = sn.w * r; o.w = hp > 0.f ? hp : (__expf(hp) - 1.f);
  *reinterpret_cast<float4*>(out + idx) = o;
}

extern "C" void kernel_launch(void* const* d_in, const int* in_sizes, int n_in,
                              void* d_out, int out_size, void* d_ws, size_t ws_size,
                              hipStream_t stream) {
  const float* h   = (const float*)d_in[0];
  const float* adj = (const float*)d_in[1];
  const float* W   = (const float*)d_in[2];
  const float* a   = (const float*)d_in[3];
  float* out = (float*)d_out;

  char* ws = (char*)d_ws;
  size_t o = 0;
  char* WhbT           = ws + o;                    o += (size_t)4 * 1024 * 1024;    // 32-col tiled
  float* s1            = (float*)(ws + o);          o += 32768;
  float* s2            = (float*)(ws + o);          o += 32768;
  float* denw          = (float*)(ws + o);          o += (size_t)KSPLIT * N * 4;     // 256 KB
  unsigned short* Wt   = (unsigned short*)(ws + o); o += 131072;
  float* numw          = (float*)(ws + o);          o += (size_t)KSPLIT * N * F * 4; // 64 MB

  hipLaunchKernelGGL(k0_wt, dim3(256), dim3(256), 0, stream, W, Wt);
  hipLaunchKernelGGL(k1_wh, dim3(N / 64), dim3(256), 0, stream, h, Wt, a, WhbT, s1, s2);
  hipLaunchKernelGGL(k3_attn, dim3(N / 128, KSPLIT), dim3(512), 0, stream,
                     adj, WhbT, s1, s2, numw, denw);
  hipLaunchKernelGGL(k4_fin, dim3(N * F / 1024), dim3(256), 0, stream, numw, denw, out);
}